// Round 2
// baseline (690.316 us; speedup 1.0000x reference)
//
#include <hip/hip_runtime.h>

#define H 1024
#define SEQ 2048
#define V 50257

// ---- output layout (flat, in return order) ----
#define OUT_CTX   50257            // context (H)
#define OUT_H0    (OUT_CTX + H)    // hidden[0] (H)
#define OUT_H1    (OUT_H0 + H)     // hidden[1] (H)
#define OUT_ATTN  (OUT_H1 + H)     // attn (SEQ)

// ---- ws layout (floats) ----
#define WS_X      0        // rnn_input (2048)
#define WS_H0     2048     // h0 (1024)
#define WS_H1     3072     // h1 (1024)
#define WS_E      4096     // energies (2048)
#define WS_ATTN   6144     // attn (2048)
#define WS_CTX    8192     // context acc (1024)
#define WS_LOGITS 9216     // logits (50257)
#define WS_PM     59473    // partial max (128)
#define WS_PS     59601    // partial sumexp (128)
#define WS_LOGZ   59729    // logZ (1)

__device__ __forceinline__ float dot4(float4 a, float4 b) {
  return a.x * b.x + a.y * b.y + a.z * b.z + a.w * b.w;
}

__device__ __forceinline__ float wave_reduce_sum(float v) {
  #pragma unroll
  for (int off = 32; off > 0; off >>= 1) v += __shfl_down(v, off);
  return v;
}

// 1) rnn_input = [emb[word], last_context] (f32), zero ctx accumulator
__global__ __launch_bounds__(256) void prep_kernel(
    const float* __restrict__ emb, const int* __restrict__ word,
    const float* __restrict__ last_context,
    float* __restrict__ rnn_input, float* __restrict__ ctx_acc) {
  int i = blockIdx.x * 256 + threadIdx.x;  // 0..1023
  int w = word[0];
  rnn_input[i]     = emb[(size_t)w * H + i];
  rnn_input[H + i] = last_context[i];
  ctx_acc[i] = 0.0f;
}

// 2/3) GRU cell: one block per output element j; 6 waves = 6 dot products
template <int XDIM>
__global__ __launch_bounds__(384) void gru_kernel(
    const float* __restrict__ x,                  // XDIM
    const float* __restrict__ hprev,              // H
    const float* __restrict__ W_ih,               // (3H, XDIM)
    const float* __restrict__ W_hh,               // (3H, H)
    const float* __restrict__ b_ih,
    const float* __restrict__ b_hh,
    float* __restrict__ h_ws, float* __restrict__ h_out) {
  int j = blockIdx.x;
  int wave = threadIdx.x >> 6, lane = threadIdx.x & 63;
  __shared__ float parts[6];
  float acc = 0.0f;
  if (wave < 3) {
    const float4* wr = (const float4*)(W_ih + (size_t)(wave * H + j) * XDIM);
    const float4* xv = (const float4*)x;
    #pragma unroll
    for (int it = 0; it < XDIM / 256; ++it) {
      int idx = it * 64 + lane;
      acc += dot4(wr[idx], xv[idx]);
    }
  } else {
    const float4* wr = (const float4*)(W_hh + (size_t)((wave - 3) * H + j) * H);
    const float4* hv = (const float4*)hprev;
    #pragma unroll
    for (int it = 0; it < H / 256; ++it) {
      int idx = it * 64 + lane;
      acc += dot4(wr[idx], hv[idx]);
    }
  }
  acc = wave_reduce_sum(acc);
  if (lane == 0) parts[wave] = acc;
  __syncthreads();
  if (threadIdx.x == 0) {
    float gi_r = parts[0] + b_ih[j];
    float gi_z = parts[1] + b_ih[H + j];
    float gi_n = parts[2] + b_ih[2 * H + j];
    float gh_r = parts[3] + b_hh[j];
    float gh_z = parts[4] + b_hh[H + j];
    float gh_n = parts[5] + b_hh[2 * H + j];
    float r = 1.0f / (1.0f + expf(-(gi_r + gh_r)));
    float z = 1.0f / (1.0f + expf(-(gi_z + gh_z)));
    float n = tanhf(gi_n + r * gh_n);
    float hp = hprev[j];
    float hn = (1.0f - z) * n + z * hp;
    h_ws[j] = hn;
    h_out[j] = hn;
  }
}

// 4) energies[s] = dot(enc[s], h1)
__global__ __launch_bounds__(256) void energies_kernel(
    const float* __restrict__ enc, const float* __restrict__ h1,
    float* __restrict__ energies) {
  int s = blockIdx.x * 4 + (threadIdx.x >> 6);
  int lane = threadIdx.x & 63;
  const float4* er = (const float4*)(enc + (size_t)s * H);
  const float4* hv = (const float4*)h1;
  float acc = 0.0f;
  #pragma unroll
  for (int it = 0; it < H / 256; ++it) {
    int idx = it * 64 + lane;
    acc += dot4(er[idx], hv[idx]);
  }
  acc = wave_reduce_sum(acc);
  if (lane == 0) energies[s] = acc;
}

// 5) softmax over SEQ=2048 energies (single block)
__global__ __launch_bounds__(1024) void softmax_kernel(
    const float* __restrict__ energies, float* __restrict__ attn_ws,
    float* __restrict__ attn_out) {
  __shared__ float red[1024];
  int t = threadIdx.x;
  float e0 = energies[t], e1 = energies[t + 1024];
  red[t] = fmaxf(e0, e1);
  __syncthreads();
  #pragma unroll
  for (int off = 512; off > 0; off >>= 1) {
    if (t < off) red[t] = fmaxf(red[t], red[t + off]);
    __syncthreads();
  }
  float M = red[0];
  __syncthreads();
  float s0 = expf(e0 - M), s1 = expf(e1 - M);
  red[t] = s0 + s1;
  __syncthreads();
  #pragma unroll
  for (int off = 512; off > 0; off >>= 1) {
    if (t < off) red[t] += red[t + off];
    __syncthreads();
  }
  float Z = red[0];
  float a0 = s0 / Z, a1 = s1 / Z;
  attn_ws[t] = a0;
  attn_ws[t + 1024] = a1;
  attn_out[t] = a0;
  attn_out[t + 1024] = a1;
}

// 6) context[h] = sum_s attn[s] * enc[s][h]  (atomicAdd into pre-zeroed acc)
__global__ __launch_bounds__(256) void context_kernel(
    const float* __restrict__ attn, const float* __restrict__ enc,
    float* __restrict__ ctx) {
  int h2 = blockIdx.x * 512 + threadIdx.x * 2;  // pair of h indices
  int s0 = blockIdx.y * 32;
  float a0 = 0.0f, a1 = 0.0f;
  for (int s = s0; s < s0 + 32; ++s) {
    float a = attn[s];
    float2 p = *(const float2*)(enc + (size_t)s * H + h2);
    a0 += a * p.x;
    a1 += a * p.y;
  }
  atomicAdd(&ctx[h2], a0);
  atomicAdd(&ctx[h2 + 1], a1);
}

// 7) logits[v] = dot(W_out[v], [h1, ctx]) + b_out[v]   — the big one
__global__ __launch_bounds__(256) void logits_kernel(
    const float* __restrict__ W_out, const float* __restrict__ b_out,
    const float* __restrict__ h1, const float* __restrict__ ctx,
    float* __restrict__ logits) {
  __shared__ float y[2 * H];
  int t = threadIdx.x;
  #pragma unroll
  for (int i = 0; i < 4; ++i) { int k = t + i * 256; y[k] = h1[k]; }
  #pragma unroll
  for (int i = 0; i < 4; ++i) { int k = t + i * 256; y[H + k] = ctx[k]; }
  __syncthreads();
  int v = blockIdx.x * 4 + (t >> 6);
  if (v >= V) return;
  int lane = t & 63;
  const float4* wr = (const float4*)(W_out + (size_t)v * (2 * H));
  const float4* yv = (const float4*)y;
  float acc = 0.0f;
  #pragma unroll
  for (int it = 0; it < (2 * H) / 256; ++it) {
    int idx = it * 64 + lane;
    acc += dot4(wr[idx], yv[idx]);
  }
  acc = wave_reduce_sum(acc);
  if (lane == 0) logits[v] = acc + b_out[v];
}

// 8) per-block (max, sumexp) partials over logits
__global__ __launch_bounds__(256) void reduce_kernel(
    const float* __restrict__ logits, float* __restrict__ pm, float* __restrict__ ps) {
  __shared__ float red[256];
  int t = threadIdx.x;
  int i0 = blockIdx.x * 256 + t;
  int i1 = i0 + 32768;
  float v0 = (i0 < V) ? logits[i0] : -INFINITY;
  float v1 = (i1 < V) ? logits[i1] : -INFINITY;
  red[t] = fmaxf(v0, v1);
  __syncthreads();
  #pragma unroll
  for (int off = 128; off > 0; off >>= 1) {
    if (t < off) red[t] = fmaxf(red[t], red[t + off]);
    __syncthreads();
  }
  float M = red[0];
  __syncthreads();
  float s = 0.0f;
  if (i0 < V) s += expf(v0 - M);
  if (i1 < V) s += expf(v1 - M);
  red[t] = s;
  __syncthreads();
  #pragma unroll
  for (int off = 128; off > 0; off >>= 1) {
    if (t < off) red[t] += red[t + off];
    __syncthreads();
  }
  if (t == 0) { pm[blockIdx.x] = M; ps[blockIdx.x] = red[0]; }
}

// 9) combine partials -> logZ
__global__ __launch_bounds__(128) void lse_final_kernel(
    const float* __restrict__ pm, const float* __restrict__ ps, float* __restrict__ logZ) {
  __shared__ float red[128];
  int t = threadIdx.x;
  float m = pm[t];
  red[t] = m;
  __syncthreads();
  #pragma unroll
  for (int off = 64; off > 0; off >>= 1) {
    if (t < off) red[t] = fmaxf(red[t], red[t + off]);
    __syncthreads();
  }
  float M = red[0];
  __syncthreads();
  red[t] = ps[t] * expf(m - M);
  __syncthreads();
  #pragma unroll
  for (int off = 64; off > 0; off >>= 1) {
    if (t < off) red[t] += red[t + off];
    __syncthreads();
  }
  if (t == 0) logZ[0] = M + logf(red[0]);
}

// 10) out[v] = logits[v] - logZ; also copy context to out
__global__ __launch_bounds__(256) void finalize_kernel(
    const float* __restrict__ logits, const float* __restrict__ logZ,
    const float* __restrict__ ctx, float* __restrict__ out) {
  int v = blockIdx.x * 256 + threadIdx.x;
  float lz = logZ[0];
  if (v < V) out[v] = logits[v] - lz;
  if (v < H) out[OUT_CTX + v] = ctx[v];
}

extern "C" void kernel_launch(void* const* d_in, const int* in_sizes, int n_in,
                              void* d_out, int out_size, void* d_ws, size_t ws_size,
                              hipStream_t stream) {
  const int*   word         = (const int*)d_in[0];
  const float* last_context = (const float*)d_in[1];
  const float* last_hidden  = (const float*)d_in[2];
  const float* enc          = (const float*)d_in[3];
  const float* emb          = (const float*)d_in[4];
  const float* W_ih0        = (const float*)d_in[5];
  const float* W_hh0        = (const float*)d_in[6];
  const float* b_ih0        = (const float*)d_in[7];
  const float* b_hh0        = (const float*)d_in[8];
  const float* W_ih1        = (const float*)d_in[9];
  const float* W_hh1        = (const float*)d_in[10];
  const float* b_ih1        = (const float*)d_in[11];
  const float* b_hh1        = (const float*)d_in[12];
  const float* W_out        = (const float*)d_in[13];
  const float* b_out        = (const float*)d_in[14];
  float* out = (float*)d_out;

  float* ws       = (float*)d_ws;
  float* rnn_in   = ws + WS_X;
  float* h0       = ws + WS_H0;
  float* h1       = ws + WS_H1;
  float* energies = ws + WS_E;
  float* attn     = ws + WS_ATTN;
  float* ctx      = ws + WS_CTX;
  float* logits   = ws + WS_LOGITS;
  float* pm       = ws + WS_PM;
  float* ps       = ws + WS_PS;
  float* logZ     = ws + WS_LOGZ;

  prep_kernel<<<4, 256, 0, stream>>>(emb, word, last_context, rnn_in, ctx);
  gru_kernel<2 * H><<<H, 384, 0, stream>>>(rnn_in, last_hidden, W_ih0, W_hh0,
                                           b_ih0, b_hh0, h0, out + OUT_H0);
  gru_kernel<H><<<H, 384, 0, stream>>>(h0, last_hidden + H, W_ih1, W_hh1,
                                       b_ih1, b_hh1, h1, out + OUT_H1);
  energies_kernel<<<SEQ / 4, 256, 0, stream>>>(enc, h1, energies);
  softmax_kernel<<<1, 1024, 0, stream>>>(energies, attn, out + OUT_ATTN);
  context_kernel<<<dim3(2, 64), 256, 0, stream>>>(attn, enc, ctx);
  logits_kernel<<<(V + 3) / 4, 256, 0, stream>>>(W_out, b_out, h1, ctx, logits);
  reduce_kernel<<<128, 256, 0, stream>>>(logits, pm, ps);
  lse_final_kernel<<<1, 128, 0, stream>>>(pm, ps, logZ);
  finalize_kernel<<<(V + 255) / 256, 256, 0, stream>>>(logits, logZ, ctx, out);
}